// Round 6
// baseline (349.805 us; speedup 1.0000x reference)
//
#include <hip/hip_runtime.h>
#include <hip/hip_bf16.h>
#include <math.h>

typedef __attribute__((ext_vector_type(8))) short bf16x8;
typedef __attribute__((ext_vector_type(4))) float f32x4;

__device__ __forceinline__ short f2bs(float x) {
  __hip_bfloat16 h = __float2bfloat16(x);
  return *reinterpret_cast<short*>(&h);
}

__device__ __forceinline__ void gll16(const void* g, void* l) {
  __builtin_amdgcn_global_load_lds(
      (const __attribute__((address_space(1))) unsigned int*)g,
      (__attribute__((address_space(3))) unsigned int*)l, 16, 0, 0);
}

// ---------------------------------------------------------------------------
// fp32 -> bf16 flat convert
// ---------------------------------------------------------------------------
__global__ __launch_bounds__(256) void cvt_f2b(
    const float* __restrict__ s, short* __restrict__ d, int n)
{
  int i = (blockIdx.x * 256 + threadIdx.x) << 2;
  if (i >= n) return;
  const float4 v = *(const float4*)(s + i);
  short4 o;
  o.x = f2bs(v.x); o.y = f2bs(v.y); o.z = f2bs(v.z); o.w = f2bs(v.w);
  *(short4*)(d + i) = o;
}

// ---------------------------------------------------------------------------
// All weight tensors -> bf16 in one launch (segments in 1024-elem blocks)
// ---------------------------------------------------------------------------
__global__ __launch_bounds__(256) void cvt_weights(
    const float* __restrict__ w0, const float* __restrict__ w1,
    const float* __restrict__ w2, const float* __restrict__ w3,
    const float* __restrict__ w4, const float* __restrict__ w5,
    const float* __restrict__ w6,
    short* __restrict__ Wcat, short* __restrict__ Wkvb, short* __restrict__ Wob)
{
  int b = blockIdx.x;
  const float* src; short* dst; int base;
  if (b < 2048)      { src = w0; dst = Wcat;           base = b; }
  else if (b < 4096) { src = w1; dst = Wcat + 2097152; base = b - 2048; }
  else if (b < 5120) { src = w2; dst = Wcat + 4194304; base = b - 4096; }
  else if (b < 5248) { src = w3; dst = Wkvb;           base = b - 5120; }
  else if (b < 5376) { src = w4; dst = Wkvb + 131072;  base = b - 5248; }
  else if (b < 5632) { src = w5; dst = Wkvb + 262144;  base = b - 5376; }
  else               { src = w6; dst = Wob;            base = b - 5632; }
  int i = base * 1024 + threadIdx.x * 4;
  float4 v = *(const float4*)(src + i);
  short4 o;
  o.x = f2bs(v.x); o.y = f2bs(v.y); o.z = f2bs(v.z); o.w = f2bs(v.w);
  *(short4*)(dst + i) = o;
}

// ---------------------------------------------------------------------------
// RMS over 512-wide rows, fp32 in -> bf16 out (one wave per row)
// ---------------------------------------------------------------------------
__global__ __launch_bounds__(256) void rms512b(
    const float* __restrict__ src, short* __restrict__ dst,
    const float* __restrict__ g, int nrows)
{
  int row = blockIdx.x * 4 + (threadIdx.x >> 6);
  int l = threadIdx.x & 63;
  if (row >= nrows) return;
  const float* p = src + (size_t)row * 512;
  float x[8];
  float ss = 0.f;
#pragma unroll
  for (int i = 0; i < 8; ++i) { x[i] = p[i * 64 + l]; ss += x[i] * x[i]; }
#pragma unroll
  for (int msk = 1; msk < 64; msk <<= 1) ss += __shfl_xor(ss, msk);
  float r = rsqrtf(ss * (1.0f / 512.0f) + 1e-6f);
#pragma unroll
  for (int i = 0; i < 8; ++i)
    dst[(size_t)row * 512 + i * 64 + l] = f2bs(x[i] * r * g[i * 64 + l]);
}

// ---------------------------------------------------------------------------
// Pure K-split MFMA GEMM: Cp[z] = A[:, z*KH:(z+1)*KH] @ W[:, same]^T (fp32)
// 128x128 tile, BK=64, 4 waves, double-buffered gll staging, counted vmcnt.
// grid (N/128, M/128, K/KH)
// ---------------------------------------------------------------------------
__global__ __launch_bounds__(256) void gemm_ks(
    const short* __restrict__ A, const short* __restrict__ W,
    float* __restrict__ C, int M, int N, int K, int KH)
{
  __shared__ short As[2][128 * 64];
  __shared__ short Bs[2][128 * 64];
  const int t = threadIdx.x;
  const int lane = t & 63, wave = t >> 6;
  const int wr = wave >> 1, wc = wave & 1;
  const int li = lane & 15, lh = lane >> 4;
  const int bm = blockIdx.y * 128, bn = blockIdx.x * 128;
  const int zoff = blockIdx.z * KH;
  float* Cp = C + (size_t)blockIdx.z * M * N;

  f32x4 acc[4][4];
#pragma unroll
  for (int m = 0; m < 4; ++m)
#pragma unroll
    for (int n = 0; n < 4; ++n) acc[m][n] = (f32x4){0.f, 0.f, 0.f, 0.f};

#define GSTAGE(buf, k0)                                                        \
  {                                                                            \
    _Pragma("unroll") for (int i = 0; i < 4; ++i) {                            \
      int id = i * 256 + t;                                                    \
      int r = id >> 3, cl = id & 7;                                            \
      gll16(A + (size_t)(bm + r) * K + zoff + (k0) + ((cl ^ (r & 7)) << 3),    \
            &As[buf][id * 8]);                                                 \
    }                                                                          \
    _Pragma("unroll") for (int i = 0; i < 4; ++i) {                            \
      int id = i * 256 + t;                                                    \
      int r = id >> 3, cl = id & 7;                                            \
      gll16(W + (size_t)(bn + r) * K + zoff + (k0) + ((cl ^ (r & 7)) << 3),    \
            &Bs[buf][id * 8]);                                                 \
    }                                                                          \
  }

  GSTAGE(0, 0);
  int cur = 0;
  for (int k0 = 0; k0 < KH; k0 += 64) {
    __builtin_amdgcn_sched_barrier(0);
    asm volatile("s_waitcnt lgkmcnt(0)" ::: "memory");
    __builtin_amdgcn_s_barrier();
    __builtin_amdgcn_sched_barrier(0);
    if (k0 + 64 < KH) {
      GSTAGE(cur ^ 1, k0 + 64);
      asm volatile("s_waitcnt vmcnt(8)" ::: "memory");
    } else {
      asm volatile("s_waitcnt vmcnt(0)" ::: "memory");
    }
    __builtin_amdgcn_sched_barrier(0);
    bf16x8 af[2][4], bf[2][4];
#pragma unroll
    for (int m = 0; m < 4; ++m) {
      int r = wr * 64 + m * 16 + li;
#pragma unroll
      for (int kd = 0; kd < 2; ++kd)
        af[kd][m] = *(const bf16x8*)&As[cur][r * 64 + (((kd * 4 + lh) ^ (r & 7)) << 3)];
    }
#pragma unroll
    for (int n = 0; n < 4; ++n) {
      int r = wc * 64 + n * 16 + li;
#pragma unroll
      for (int kd = 0; kd < 2; ++kd)
        bf[kd][n] = *(const bf16x8*)&Bs[cur][r * 64 + (((kd * 4 + lh) ^ (r & 7)) << 3)];
    }
    __builtin_amdgcn_s_setprio(1);
#pragma unroll
    for (int kd = 0; kd < 2; ++kd)
#pragma unroll
      for (int m = 0; m < 4; ++m)
#pragma unroll
        for (int n = 0; n < 4; ++n)
          acc[m][n] = __builtin_amdgcn_mfma_f32_16x16x32_bf16(af[kd][m], bf[kd][n],
                                                              acc[m][n], 0, 0, 0);
    __builtin_amdgcn_s_setprio(0);
    __builtin_amdgcn_sched_barrier(0);
    cur ^= 1;
  }
#undef GSTAGE

#pragma unroll
  for (int m = 0; m < 4; ++m) {
    int gm = bm + wr * 64 + m * 16 + lh * 4;
#pragma unroll
    for (int n = 0; n < 4; ++n) {
      int gn = bn + wc * 64 + n * 16 + li;
#pragma unroll
      for (int j = 0; j < 4; ++j)
        Cp[(size_t)(gm + j) * N + gn] = acc[m][n][j];
    }
  }
}

// ---------------------------------------------------------------------------
// ep_q: sum qkv partials; cols<1024 RMS->qb nope | 1024..2047 RMS+rope->qb
// rope | >=2048 raw sum -> ckv_f.  grid (10, 2048), wave per 64-col group.
// ---------------------------------------------------------------------------
__global__ __launch_bounds__(256) void ep_q(
    const float* __restrict__ P0, const float* __restrict__ P1,
    short* __restrict__ qb, float* __restrict__ ckv_f,
    const float* __restrict__ cosb, const float* __restrict__ sinb,
    const float* __restrict__ g_qnope, const float* __restrict__ g_qrope)
{
  const int r = blockIdx.y;
  const int cg = blockIdx.x * 4 + (threadIdx.x >> 6);
  const int l = threadIdx.x & 63;
  const int n = cg * 64 + l;
  float val = P0[(size_t)r * 2560 + n] + P1[(size_t)r * 2560 + n];
  if (cg >= 32) {  // ckv
    ckv_f[(size_t)r * 512 + (n - 2048)] = val;
    return;
  }
  const bool rope = cg >= 16;
  float ss = val * val;
#pragma unroll
  for (int msk = 1; msk < 64; msk <<= 1) ss += __shfl_xor(ss, msk);
  float rr = rsqrtf(ss * (1.0f / 64.0f) + 1e-6f);
  float y = val * rr * (rope ? g_qrope[l] : g_qnope[l]);
  if (rope) {
    float partner = __shfl_xor(y, 32);
    float c = cosb[r * 64 + l], sn = sinb[r * 64 + l];
    y = y * c + ((l < 32) ? -partner : partner) * sn;
  }
  const int head = cg & 15;
  qb[(size_t)r * 2048 + head * 128 + (rope ? 64 : 0) + l] = f2bs(y);
}

// ---------------------------------------------------------------------------
// ep_kv: sum kv partials for cols 0..511 -> kb (rope on 256..511).
// grid (2, 2048), wave per 64-col group.
// ---------------------------------------------------------------------------
__global__ __launch_bounds__(256) void ep_kv(
    const float* __restrict__ P0, const float* __restrict__ P1,
    short* __restrict__ kb,
    const float* __restrict__ cosb, const float* __restrict__ sinb)
{
  const int r = blockIdx.y;
  const int cg = blockIdx.x * 4 + (threadIdx.x >> 6);  // 0..7
  const int l = threadIdx.x & 63;
  const int n = cg * 64 + l;
  float y = P0[(size_t)r * 1024 + n] + P1[(size_t)r * 1024 + n];
  const bool rope = cg >= 4;
  if (rope) {
    float partner = __shfl_xor(y, 32);
    float c = cosb[r * 64 + l], sn = sinb[r * 64 + l];
    y = y * c + ((l < 32) ? -partner : partner) * sn;
  }
  const int kvh = cg & 3;
  kb[(size_t)r * 512 + kvh * 128 + (rope ? 64 : 0) + l] = f2bs(y);
}

// ---------------------------------------------------------------------------
// ep_vt: sum kv partials for cols 512..1023 (v) -> vt bf16 [4][128][S]
// grid (st=32, dh=2, kvh=4), 64x64 LDS tile transpose.
// ---------------------------------------------------------------------------
__global__ __launch_bounds__(256) void ep_vt(
    const float* __restrict__ P0, const float* __restrict__ P1,
    short* __restrict__ vt)
{
  __shared__ float tile[64][65];
  const int st = blockIdx.x, dh = blockIdx.y, kvh = blockIdx.z;
  const int r4 = threadIdx.x >> 6, cl = threadIdx.x & 63;
  const int col = 512 + kvh * 128 + dh * 64 + cl;
#pragma unroll
  for (int i = 0; i < 16; ++i) {
    int srow = i * 4 + r4;
    size_t idx = (size_t)(st * 64 + srow) * 1024 + col;
    tile[srow][cl] = P0[idx] + P1[idx];
  }
  __syncthreads();
#pragma unroll
  for (int i = 0; i < 16; ++i) {
    int drow = i * 4 + r4;
    vt[(size_t)kvh * 262144 + (size_t)(dh * 64 + drow) * 2048 + st * 64 + cl] =
        f2bs(tile[cl][drow]);
  }
}

// ---------------------------------------------------------------------------
// ep_out: out = P0 + P1 (fp32, 2048x2048)
// ---------------------------------------------------------------------------
__global__ __launch_bounds__(256) void ep_out(
    const float* __restrict__ P0, const float* __restrict__ P1,
    float* __restrict__ out)
{
  int i = (blockIdx.x * 256 + threadIdx.x) << 2;
  float4 a = *(const float4*)(P0 + i);
  float4 b = *(const float4*)(P1 + i);
  float4 o;
  o.x = a.x + b.x; o.y = a.y + b.y; o.z = a.z + b.z; o.w = a.w + b.w;
  *(float4*)(out + i) = o;
}

// ---------------------------------------------------------------------------
// MFMA flash attention, causal. 2 waves x 32 q-rows (BQ=64), BK=64, HD=128.
// Double-buffered K/V via gll16 with counted vmcnt; base-2 online softmax.
// qb [S][16*128], kb [S][4*128], vt [4][128][S], ob bf16 [S][16*128]
// grid (16 heads, 32 qt), block 128.
// ---------------------------------------------------------------------------
__global__ __launch_bounds__(128) void attn_mfma(
    const short* __restrict__ qb, const short* __restrict__ kb,
    const short* __restrict__ vt, short* __restrict__ ob)
{
  __shared__ short Ks[2][64 * 128];   // [kpos][d] swizzled
  __shared__ short Vs[2][128 * 64];   // [d][kpos] swizzled
  __shared__ short Ps[2][32 * 64];    // per-wave [q][kpos] swizzled
  const int h = blockIdx.x;
  const int qt = gridDim.y - 1 - blockIdx.y;  // longest blocks first
  const int kvh = h >> 2;
  const int t = threadIdx.x, lane = t & 63, wave = t >> 6;
  const int li = lane & 15, lh = lane >> 4;
  const int q0 = qt * 64, q0w = q0 + wave * 32;
  const float sc2 = 0.08838834764831845f * 1.44269504088896f;  // /sqrt(128)*log2e

  bf16x8 qf[2][4];
#pragma unroll
  for (int rf = 0; rf < 2; ++rf)
#pragma unroll
    for (int kd = 0; kd < 4; ++kd)
      qf[rf][kd] = *(const bf16x8*)(qb + (size_t)(q0w + rf * 16 + li) * 2048 +
                                    h * 128 + kd * 32 + lh * 8);

  f32x4 o[2][8];
#pragma unroll
  for (int rf = 0; rf < 2; ++rf)
#pragma unroll
    for (int n = 0; n < 8; ++n) o[rf][n] = (f32x4){0.f, 0.f, 0.f, 0.f};
  float m_i[2][4], l_i[2][4];
#pragma unroll
  for (int rf = 0; rf < 2; ++rf)
#pragma unroll
    for (int j = 0; j < 4; ++j) { m_i[rf][j] = -1e30f; l_i[rf][j] = 0.f; }

#define ASTAGE(buf, kbase)                                                     \
  {                                                                            \
    _Pragma("unroll") for (int i = 0; i < 8; ++i) {                            \
      int c = t + i * 128;                                                     \
      int kpos = c >> 4, dcl = (c & 15) ^ (kpos & 7);                          \
      gll16(kb + (size_t)((kbase) + kpos) * 512 + kvh * 128 + dcl * 8,         \
            &Ks[buf][c * 8]);                                                  \
    }                                                                          \
    _Pragma("unroll") for (int i = 0; i < 8; ++i) {                            \
      int c = t + i * 128;                                                     \
      int d = c >> 3, kpl = (c & 7) ^ (d & 7);                                 \
      gll16(vt + (size_t)kvh * 262144 + (size_t)d * 2048 + (kbase) + kpl * 8,  \
            &Vs[buf][c * 8]);                                                  \
    }                                                                          \
  }

  short* pw = Ps[wave];
  const int nkt = qt + 1;
  ASTAGE(0, 0);
  int cur = 0;
  for (int kt = 0; kt < nkt; ++kt) {
    const int kbase = kt * 64;
    __builtin_amdgcn_sched_barrier(0);
    asm volatile("s_waitcnt lgkmcnt(0)" ::: "memory");
    __builtin_amdgcn_s_barrier();
    __builtin_amdgcn_sched_barrier(0);
    if (kt + 1 < nkt) {
      ASTAGE(cur ^ 1, kbase + 64);
      asm volatile("s_waitcnt vmcnt(16)" ::: "memory");
    } else {
      asm volatile("s_waitcnt vmcnt(0)" ::: "memory");
    }
    __builtin_amdgcn_sched_barrier(0);

    // ---- S = Q K^T ----
    f32x4 s[2][4];
#pragma unroll
    for (int rf = 0; rf < 2; ++rf)
#pragma unroll
      for (int n = 0; n < 4; ++n) s[rf][n] = (f32x4){0.f, 0.f, 0.f, 0.f};
    __builtin_amdgcn_s_setprio(1);
#pragma unroll
    for (int n = 0; n < 4; ++n) {
      int kpos = n * 16 + li;
#pragma unroll
      for (int kd = 0; kd < 4; ++kd) {
        int cph = (kd * 4 + lh) ^ (kpos & 7);
        bf16x8 kf = *(const bf16x8*)&Ks[cur][kpos * 128 + cph * 8];
        s[0][n] = __builtin_amdgcn_mfma_f32_16x16x32_bf16(qf[0][kd], kf, s[0][n], 0, 0, 0);
        s[1][n] = __builtin_amdgcn_mfma_f32_16x16x32_bf16(qf[1][kd], kf, s[1][n], 0, 0, 0);
      }
    }
    __builtin_amdgcn_s_setprio(0);
    // ---- scale (base-2) + causal mask ----
    float sv[2][4][4];
    const bool dg = (kbase + 63 > q0w);
#pragma unroll
    for (int rf = 0; rf < 2; ++rf)
#pragma unroll
      for (int n = 0; n < 4; ++n)
#pragma unroll
        for (int j = 0; j < 4; ++j) {
          float val = s[rf][n][j] * sc2;
          if (dg) {
            int kg = kbase + n * 16 + li;
            int qg = q0w + rf * 16 + lh * 4 + j;
            if (kg > qg) val = -1e30f;
          }
          sv[rf][n][j] = val;
        }
    // ---- online softmax (base 2) ----
    float c_[2][4];
    float cmin = 1.f;
#pragma unroll
    for (int rf = 0; rf < 2; ++rf)
#pragma unroll
      for (int j = 0; j < 4; ++j) {
        float rm = fmaxf(fmaxf(sv[rf][0][j], sv[rf][1][j]),
                         fmaxf(sv[rf][2][j], sv[rf][3][j]));
        rm = fmaxf(rm, __shfl_xor(rm, 1));
        rm = fmaxf(rm, __shfl_xor(rm, 2));
        rm = fmaxf(rm, __shfl_xor(rm, 4));
        rm = fmaxf(rm, __shfl_xor(rm, 8));
        float mn = fmaxf(m_i[rf][j], rm);
        c_[rf][j] = exp2f(m_i[rf][j] - mn);
        m_i[rf][j] = mn;
        cmin = fminf(cmin, c_[rf][j]);
      }
#pragma unroll
    for (int rf = 0; rf < 2; ++rf)
#pragma unroll
      for (int n = 0; n < 4; ++n)
#pragma unroll
        for (int j = 0; j < 4; ++j) sv[rf][n][j] = exp2f(sv[rf][n][j] - m_i[rf][j]);
#pragma unroll
    for (int rf = 0; rf < 2; ++rf)
#pragma unroll
      for (int j = 0; j < 4; ++j) {
        float rs = sv[rf][0][j] + sv[rf][1][j] + sv[rf][2][j] + sv[rf][3][j];
        rs += __shfl_xor(rs, 1);
        rs += __shfl_xor(rs, 2);
        rs += __shfl_xor(rs, 4);
        rs += __shfl_xor(rs, 8);
        l_i[rf][j] = l_i[rf][j] * c_[rf][j] + rs;
      }
    // ---- P -> LDS (bf16, swizzled; per-wave buffer) ----
#pragma unroll
    for (int rf = 0; rf < 2; ++rf)
#pragma unroll
      for (int n = 0; n < 4; ++n)
#pragma unroll
        for (int j = 0; j < 4; ++j) {
          int qq = rf * 16 + lh * 4 + j, kp = n * 16 + li;
          pw[qq * 64 + (kp ^ ((qq & 7) << 3))] = f2bs(sv[rf][n][j]);
        }
    // ---- rescale O (skip when all c == 1) ----
    if (__any(cmin < 1.f)) {
#pragma unroll
      for (int rf = 0; rf < 2; ++rf)
#pragma unroll
        for (int n = 0; n < 8; ++n)
#pragma unroll
          for (int j = 0; j < 4; ++j) o[rf][n][j] *= c_[rf][j];
    }
    // same-wave LDS write->read fence (rule #18)
    asm volatile("s_waitcnt lgkmcnt(0)" ::: "memory");
    __builtin_amdgcn_sched_barrier(0);
    // ---- O += P V ----
    __builtin_amdgcn_s_setprio(1);
#pragma unroll
    for (int kk = 0; kk < 2; ++kk) {
      int kp0 = kk * 32 + lh * 8;
      bf16x8 pf0 = *(const bf16x8*)&pw[li * 64 + (kp0 ^ ((li & 7) << 3))];
      bf16x8 pf1 = *(const bf16x8*)&pw[(16 + li) * 64 + (kp0 ^ ((li & 7) << 3))];
#pragma unroll
      for (int n = 0; n < 8; ++n) {
        int d = n * 16 + li;
        bf16x8 vf = *(const bf16x8*)&Vs[cur][d * 64 + (kp0 ^ ((d & 7) << 3))];
        o[0][n] = __builtin_amdgcn_mfma_f32_16x16x32_bf16(pf0, vf, o[0][n], 0, 0, 0);
        o[1][n] = __builtin_amdgcn_mfma_f32_16x16x32_bf16(pf1, vf, o[1][n], 0, 0, 0);
      }
    }
    __builtin_amdgcn_s_setprio(0);
    __builtin_amdgcn_sched_barrier(0);
    cur ^= 1;
  }
#undef ASTAGE
#pragma unroll
  for (int rf = 0; rf < 2; ++rf) {
    float inv[4];
#pragma unroll
    for (int j = 0; j < 4; ++j) inv[j] = 1.0f / l_i[rf][j];
#pragma unroll
    for (int n = 0; n < 8; ++n)
#pragma unroll
      for (int j = 0; j < 4; ++j)
        ob[(size_t)(q0w + rf * 16 + lh * 4 + j) * 2048 + h * 128 + n * 16 + li] =
            f2bs(o[rf][n][j] * inv[j]);
  }
}

// ---------------------------------------------------------------------------
extern "C" void kernel_launch(void* const* d_in, const int* in_sizes, int n_in,
                              void* d_out, int out_size, void* d_ws, size_t ws_size,
                              hipStream_t stream) {
  const float* x         = (const float*)d_in[0];
  const float* cosb      = (const float*)d_in[1];
  const float* sinb      = (const float*)d_in[2];
  const float* Wq_nope   = (const float*)d_in[3];
  const float* Wq_rope   = (const float*)d_in[4];
  const float* g_qnope   = (const float*)d_in[5];
  const float* g_qrope   = (const float*)d_in[6];
  const float* W_kv_down = (const float*)d_in[7];
  const float* g_ckv     = (const float*)d_in[8];
  const float* W_k_nope  = (const float*)d_in[9];
  const float* W_k_rope  = (const float*)d_in[10];
  const float* W_v       = (const float*)d_in[11];
  const float* W_o       = (const float*)d_in[12];
  float* out = (float*)d_out;

  float* ws = (float*)d_ws;
  // fp32 partial region (reused): qkv partials then W_o partials
  float* Pq0 = ws;                     // 2048*2560 = 5,242,880
  float* Pq1 = ws + 5242880;           // 5,242,880
  float* Po0 = ws;                     // 2048*2048 (after Pq dead)
  float* Po1 = ws + 4194304;
  float* ckv_f = ws + 10485760;        // 1,048,576
  short* sb = (short*)(ws + 11534336);
  short* xb   = sb;                    // 4,194,304 (dead after gemm1)
  short* Wcat = sb + 4194304;          // 5,242,880 (dead after gemm1)
  // kv partials overlay xb+Wcat region (after gemm1): 2 x 2048*1024 floats
  float* Pkv0 = (float*)sb;
  float* Pkv1 = (float*)sb + 2097152;
  // attn output overlays same region (after ep_kv/ep_vt)
  short* aob  = sb;                    // 4,194,304
  short* Wkvb = sb + 9437184;          //   524,288
  short* Wob  = sb + 9961472;          // 4,194,304
  short* qb   = sb + 14155776;         // 4,194,304
  short* ckvb = sb + 18350080;         // 1,048,576
  short* kb   = sb + 19398656;         // 1,048,576
  short* vt   = sb + 20447232;         // 1,048,576

  dim3 blk(256);

  cvt_f2b<<<4096, blk, 0, stream>>>(x, xb, 4194304);
  cvt_weights<<<9728, blk, 0, stream>>>(Wq_nope, Wq_rope, W_kv_down, W_k_nope,
                                        W_k_rope, W_v, W_o, Wcat, Wkvb, Wob);

  // qkv projection: x @ [Wq_nope; Wq_rope; W_kv_down]^T (N=2560, K=2048, split 2)
  gemm_ks<<<dim3(20, 16, 2), blk, 0, stream>>>(xb, Wcat, Pq0, 2048, 2560, 2048, 1024);
  ep_q<<<dim3(10, 2048), blk, 0, stream>>>(Pq0, Pq1, qb, ckv_f, cosb, sinb,
                                           g_qnope, g_qrope);
  rms512b<<<512, blk, 0, stream>>>(ckv_f, ckvb, g_ckv, 2048);

  // kv projection: ckv @ [W_k_nope; W_k_rope; W_v]^T (N=1024, K=512, split 2)
  gemm_ks<<<dim3(8, 16, 2), blk, 0, stream>>>(ckvb, Wkvb, Pkv0, 2048, 1024, 512, 256);
  ep_kv<<<dim3(2, 2048), blk, 0, stream>>>(Pkv0, Pkv1, kb, cosb, sinb);
  ep_vt<<<dim3(32, 2, 4), blk, 0, stream>>>(Pkv0, Pkv1, vt);

  // attention
  attn_mfma<<<dim3(16, 32), dim3(128), 0, stream>>>(qb, kb, vt, aob);

  // output projection: ao @ W_o^T (N=2048, K=2048, split 2)
  gemm_ks<<<dim3(16, 16, 2), blk, 0, stream>>>(aob, Wob, Po0, 2048, 2048, 2048, 1024);
  ep_out<<<4096, blk, 0, stream>>>(Po0, Po1, out);
}